// Round 1
// baseline (180.174 us; speedup 1.0000x reference)
//
#include <hip/hip_runtime.h>

#define B_TOT 8192
#define PP 32
#define QQ 32
#define RR 8
#define H1 128
#define H2 64
#define PHH 16
#define PAIRS 1024
#define OUT_UNITS 8192

__global__ void zero_out_k(float* __restrict__ out, int n) {
    int i = blockIdx.x * blockDim.x + threadIdx.x;
    if (i < n) out[i] = 0.f;
}

// Main-effect MLPs: grid (btile=128, half=2, which=2), block 256 (4 waves).
// Each wave: lane = batch element (64 b's per block); phase A computes a
// 32-neuron j-slice of h1 for all 64 b's; phase B computes an 8-neuron h2
// slice reading h1 from LDS. Weights indexed wave-uniformly -> scalar loads.
__global__ __launch_bounds__(256) void main_mlps_k(
    const float* __restrict__ x, const float* __restrict__ z,
    const float* __restrict__ xw1, const float* __restrict__ xb1,
    const float* __restrict__ xw2, const float* __restrict__ xb2,
    const float* __restrict__ xw3, const float* __restrict__ xb3,
    const float* __restrict__ zw1, const float* __restrict__ zb1,
    const float* __restrict__ zw2, const float* __restrict__ zb2,
    const float* __restrict__ zw3, const float* __restrict__ zb3,
    float* __restrict__ out)
{
    const int btile = blockIdx.x;
    const int hf    = blockIdx.y;
    const int which = blockIdx.z;
    const float* in = which ? z   : x;
    const float* w1 = which ? zw1 : xw1;
    const float* b1 = which ? zb1 : xb1;
    const float* w2 = which ? zw2 : xw2;
    const float* b2 = which ? zb2 : xb2;
    const float* w3 = which ? zw3 : xw3;
    const float* b3 = which ? zb3 : xb3;

    __shared__ float inT[32][65];    // [m][b] transposed input tile
    __shared__ float h1T[128][65];   // [j][b]

    const int t    = threadIdx.x;
    const int w    = __builtin_amdgcn_readfirstlane(t >> 6); // wave id, wave-uniform
    const int lane = t & 63;
    const int b0   = btile * 64;

    // stage input tile (64 rows x 32 cols) transposed into LDS
    const float4* src = reinterpret_cast<const float4*>(in + (size_t)b0 * 32);
    #pragma unroll
    for (int it = 0; it < 2; ++it) {
        int fi = t + it * 256;            // 512 float4 total
        float4 v = src[fi];
        int bb = fi >> 3;
        int m  = (fi & 7) * 4;
        inT[m][bb] = v.x; inT[m+1][bb] = v.y; inT[m+2][bb] = v.z; inT[m+3][bb] = v.w;
    }
    __syncthreads();

    // phase A: h1[j] for j in [32w, 32w+32), all 64 b's (lane = b)
    float h1[32];
    #pragma unroll
    for (int j = 0; j < 32; ++j) h1[j] = b1[w*32 + j];
    #pragma unroll 4
    for (int m = 0; m < 32; ++m) {
        float xv = inT[m][lane];
        #pragma unroll
        for (int j = 0; j < 32; ++j)
            h1[j] = fmaf(xv, w1[m*H1 + w*32 + j], h1[j]);
    }
    #pragma unroll
    for (int j = 0; j < 32; ++j)
        h1T[w*32 + j][lane] = fmaxf(h1[j], 0.f);
    __syncthreads();

    // phase B: h2[n] for n in [hf*32 + 8w, +8)
    const int n0 = __builtin_amdgcn_readfirstlane(hf*32 + w*8);
    float h2[8];
    #pragma unroll
    for (int n = 0; n < 8; ++n) h2[n] = b2[n0 + n];
    #pragma unroll 4
    for (int m = 0; m < 128; ++m) {
        float hv = h1T[m][lane];
        #pragma unroll
        for (int n = 0; n < 8; ++n)
            h2[n] = fmaf(hv, w2[m*H2 + n0 + n], h2[n]);
    }
    float p = 0.f;
    #pragma unroll
    for (int n = 0; n < 8; ++n)
        p = fmaf(fmaxf(h2[n], 0.f), w3[n0 + n], p);
    if (hf == 0 && w == 0) p += b3[0];    // output bias, once per (which, b)
    atomicAdd(out + b0 + lane, p);
}

// Interaction: grid (128 b-tiles, 16 pair-tiles), block 256 (4 waves).
// Wave handles 16 consecutive pairs (all same i) for 64 b's (lane = b).
// h[r] = relu(x_i*wx + z_k*wz + b); t[j] = relu(h . pw1[:,j] + pb1);
// acc += t . pw2. All weights wave-uniform -> scalar loads.
__global__ __launch_bounds__(256) void interact_k(
    const float* __restrict__ x, const float* __restrict__ z,
    const float* __restrict__ xzw, const float* __restrict__ xzb,
    const float* __restrict__ pw1, const float* __restrict__ pb1,
    const float* __restrict__ pw2, float* __restrict__ out)
{
    __shared__ float xT[32][65];
    __shared__ float zT[32][65];

    const int t    = threadIdx.x;
    const int w    = t >> 6;
    const int lane = t & 63;
    const int b0   = blockIdx.x * 64;
    const int p0   = __builtin_amdgcn_readfirstlane(blockIdx.y * 64 + w * 16);

    const float4* sx = reinterpret_cast<const float4*>(x + (size_t)b0 * 32);
    const float4* sz = reinterpret_cast<const float4*>(z + (size_t)b0 * 32);
    #pragma unroll
    for (int it = 0; it < 2; ++it) {
        int fi = t + it * 256;
        float4 v = sx[fi];
        float4 u = sz[fi];
        int bb = fi >> 3;
        int m  = (fi & 7) * 4;
        xT[m][bb] = v.x; xT[m+1][bb] = v.y; xT[m+2][bb] = v.z; xT[m+3][bb] = v.w;
        zT[m][bb] = u.x; zT[m+1][bb] = u.y; zT[m+2][bb] = u.z; zT[m+3][bb] = u.w;
    }
    __syncthreads();

    const int i = p0 >> 5;            // constant over this wave's 16 pairs
    const float xv = xT[i][lane];
    float acc0 = 0.f, acc1 = 0.f, acc2 = 0.f, acc3 = 0.f;

    #pragma unroll 1
    for (int kk = 0; kk < 16; ++kk) {
        const int p = p0 + kk;
        const int k = p & 31;
        const float zv = zT[k][lane];

        const float* __restrict__ wx = xzw + i * OUT_UNITS + p * RR;
        const float* __restrict__ wz = xzw + (PP + k) * OUT_UNITS + p * RR;
        const float* __restrict__ hb = xzb + p * RR;
        float h[8];
        #pragma unroll
        for (int r = 0; r < 8; ++r)
            h[r] = fmaxf(fmaf(zv, wz[r], fmaf(xv, wx[r], hb[r])), 0.f);

        const float* __restrict__ w1p = pw1 + p * (RR * PHH);
        const float* __restrict__ b1p = pb1 + p * PHH;
        float tv[16];
        #pragma unroll
        for (int j = 0; j < 16; ++j) tv[j] = b1p[j];
        #pragma unroll
        for (int r = 0; r < 8; ++r) {
            #pragma unroll
            for (int j = 0; j < 16; ++j)
                tv[j] = fmaf(h[r], w1p[r*16 + j], tv[j]);
        }
        const float* __restrict__ w2p = pw2 + p * PHH;
        #pragma unroll
        for (int j = 0; j < 16; j += 4) {
            acc0 = fmaf(fmaxf(tv[j+0], 0.f), w2p[j+0], acc0);
            acc1 = fmaf(fmaxf(tv[j+1], 0.f), w2p[j+1], acc1);
            acc2 = fmaf(fmaxf(tv[j+2], 0.f), w2p[j+2], acc2);
            acc3 = fmaf(fmaxf(tv[j+3], 0.f), w2p[j+3], acc3);
        }
    }
    atomicAdd(out + b0 + lane, (acc0 + acc1) + (acc2 + acc3));
}

extern "C" void kernel_launch(void* const* d_in, const int* in_sizes, int n_in,
                              void* d_out, int out_size, void* d_ws, size_t ws_size,
                              hipStream_t stream) {
    const float* x   = (const float*)d_in[0];
    const float* z   = (const float*)d_in[1];
    const float* xw1 = (const float*)d_in[2];
    const float* xb1 = (const float*)d_in[3];
    const float* xw2 = (const float*)d_in[4];
    const float* xb2 = (const float*)d_in[5];
    const float* xw3 = (const float*)d_in[6];
    const float* xb3 = (const float*)d_in[7];
    const float* zw1 = (const float*)d_in[8];
    const float* zb1 = (const float*)d_in[9];
    const float* zw2 = (const float*)d_in[10];
    const float* zb2 = (const float*)d_in[11];
    const float* zw3 = (const float*)d_in[12];
    const float* zb3 = (const float*)d_in[13];
    const float* xzw = (const float*)d_in[14];
    const float* xzb = (const float*)d_in[15];
    const float* pw1 = (const float*)d_in[16];
    const float* pb1 = (const float*)d_in[17];
    const float* pw2 = (const float*)d_in[18];
    float* out = (float*)d_out;

    zero_out_k<<<(out_size + 255) / 256, 256, 0, stream>>>(out, out_size);

    main_mlps_k<<<dim3(B_TOT / 64, 2, 2), 256, 0, stream>>>(
        x, z, xw1, xb1, xw2, xb2, xw3, xb3,
        zw1, zb1, zw2, zb2, zw3, zb3, out);

    interact_k<<<dim3(B_TOT / 64, PAIRS / 64), 256, 0, stream>>>(
        x, z, xzw, xzb, pw1, pb1, pw2, out);
}

// Round 2
// 178.817 us; speedup vs baseline: 1.0076x; 1.0076x over previous
//
#include <hip/hip_runtime.h>

#define B_TOT 8192
#define PP 32
#define QQ 32
#define RR 8
#define H1 128
#define H2 64
#define PHH 16
#define PAIRS 1024
#define OUT_UNITS 8192

typedef float v2f __attribute__((ext_vector_type(2)));

__global__ void zero_out_k(float* __restrict__ out, int n) {
    int i = blockIdx.x * blockDim.x + threadIdx.x;
    if (i < n) out[i] = 0.f;
}

// Main-effect MLPs: grid (btile=128, half=2, which=2), block 256 (4 waves).
// lane = batch element; packed-fp32 (v2f over neuron pairs) inner loops;
// weights at wave-uniform addresses -> s_load, broadcast into v_pk_fma_f32.
__global__ __launch_bounds__(256) void main_mlps_k(
    const float* __restrict__ x, const float* __restrict__ z,
    const float* __restrict__ xw1, const float* __restrict__ xb1,
    const float* __restrict__ xw2, const float* __restrict__ xb2,
    const float* __restrict__ xw3, const float* __restrict__ xb3,
    const float* __restrict__ zw1, const float* __restrict__ zb1,
    const float* __restrict__ zw2, const float* __restrict__ zb2,
    const float* __restrict__ zw3, const float* __restrict__ zb3,
    float* __restrict__ out)
{
    const int btile = blockIdx.x;
    const int hf    = blockIdx.y;
    const int which = blockIdx.z;
    const float* in = which ? z   : x;
    const float* w1 = which ? zw1 : xw1;
    const float* b1 = which ? zb1 : xb1;
    const float* w2 = which ? zw2 : xw2;
    const float* b2 = which ? zb2 : xb2;
    const float* w3 = which ? zw3 : xw3;
    const float* b3 = which ? zb3 : xb3;

    __shared__ float inT[32][65];    // [m][b] transposed input tile
    __shared__ float h1T[128][65];   // [j][b]

    const int t    = threadIdx.x;
    const int w    = __builtin_amdgcn_readfirstlane(t >> 6);
    const int lane = t & 63;
    const int b0   = btile * 64;

    const float4* src = reinterpret_cast<const float4*>(in + (size_t)b0 * 32);
    #pragma unroll
    for (int it = 0; it < 2; ++it) {
        int fi = t + it * 256;            // 512 float4 total
        float4 v = src[fi];
        int bb = fi >> 3;
        int m  = (fi & 7) * 4;
        inT[m][bb] = v.x; inT[m+1][bb] = v.y; inT[m+2][bb] = v.z; inT[m+3][bb] = v.w;
    }
    __syncthreads();

    const v2f zero = {0.f, 0.f};

    // phase A: h1[j] for j in [32w, 32w+32), lane = b; v2f over j-pairs
    v2f h1[16];
    const v2f* b1v = reinterpret_cast<const v2f*>(b1 + w * 32);
    #pragma unroll
    for (int j = 0; j < 16; ++j) h1[j] = b1v[j];
    #pragma unroll 4
    for (int m = 0; m < 32; ++m) {
        float xv = inT[m][lane];
        const v2f* w1v = reinterpret_cast<const v2f*>(w1 + m * H1 + w * 32);
        #pragma unroll
        for (int j = 0; j < 16; ++j)
            h1[j] = xv * w1v[j] + h1[j];
    }
    #pragma unroll
    for (int j = 0; j < 16; ++j) {
        v2f r = __builtin_elementwise_max(h1[j], zero);
        h1T[w*32 + 2*j    ][lane] = r.x;
        h1T[w*32 + 2*j + 1][lane] = r.y;
    }
    __syncthreads();

    // phase B: h2[n] for n in [hf*32 + 8w, +8); v2f over n-pairs
    const int n0 = __builtin_amdgcn_readfirstlane(hf*32 + w*8);
    const v2f* b2v = reinterpret_cast<const v2f*>(b2 + n0);
    v2f h2[4];
    #pragma unroll
    for (int n = 0; n < 4; ++n) h2[n] = b2v[n];
    #pragma unroll 4
    for (int m = 0; m < 128; ++m) {
        float hv = h1T[m][lane];
        const v2f* w2v = reinterpret_cast<const v2f*>(w2 + m * H2 + n0);
        #pragma unroll
        for (int n = 0; n < 4; ++n)
            h2[n] = hv * w2v[n] + h2[n];
    }
    const v2f* w3v = reinterpret_cast<const v2f*>(w3 + n0);
    v2f pv = zero;
    #pragma unroll
    for (int n = 0; n < 4; ++n)
        pv = __builtin_elementwise_max(h2[n], zero) * w3v[n] + pv;
    float p = pv.x + pv.y;
    if (hf == 0 && w == 0) p += b3[0];
    atomicAdd(out + b0 + lane, p);
}

// Interaction: grid (64 b-tiles of 128, 16 pair-tiles), block 256 (4 waves).
// Wave handles 16 consecutive pairs (same i) for 128 b's (2 per lane, packed
// in a v2f). All weights wave-uniform -> s_load; math is v_pk_fma_f32 with
// the weight broadcast from SGPR.
__global__ __launch_bounds__(256) void interact_k(
    const float* __restrict__ x, const float* __restrict__ z,
    const float* __restrict__ xzw, const float* __restrict__ xzb,
    const float* __restrict__ pw1, const float* __restrict__ pb1,
    const float* __restrict__ pw2, float* __restrict__ out)
{
    __shared__ float xT[32][130];   // [m][b], 128 batches + pad (8B-aligned rows)
    __shared__ float zT[32][130];

    const int t    = threadIdx.x;
    const int w    = t >> 6;
    const int lane = t & 63;
    const int b0   = blockIdx.x * 128;
    const int p0   = __builtin_amdgcn_readfirstlane(blockIdx.y * 64 + w * 16);

    const float4* sx = reinterpret_cast<const float4*>(x + (size_t)b0 * 32);
    const float4* sz = reinterpret_cast<const float4*>(z + (size_t)b0 * 32);
    #pragma unroll
    for (int it = 0; it < 4; ++it) {
        int fi = t + it * 256;            // 1024 float4 per input
        float4 v = sx[fi];
        float4 u = sz[fi];
        int bb = fi >> 3;                 // batch 0..127
        int m  = (fi & 7) * 4;
        xT[m][bb] = v.x; xT[m+1][bb] = v.y; xT[m+2][bb] = v.z; xT[m+3][bb] = v.w;
        zT[m][bb] = u.x; zT[m+1][bb] = u.y; zT[m+2][bb] = u.z; zT[m+3][bb] = u.w;
    }
    __syncthreads();

    const v2f zero = {0.f, 0.f};
    const int i = p0 >> 5;                 // constant over this wave's 16 pairs
    const v2f xv = *reinterpret_cast<const v2f*>(&xT[i][2*lane]);  // batches 2*lane, 2*lane+1

    v2f acc0 = zero, acc1 = zero, acc2 = zero, acc3 = zero;

    #pragma unroll 2
    for (int kk = 0; kk < 16; ++kk) {
        const int p = p0 + kk;
        const int k = p & 31;
        const v2f zv = *reinterpret_cast<const v2f*>(&zT[k][2*lane]);

        const float* __restrict__ wx = xzw + i * OUT_UNITS + p * RR;
        const float* __restrict__ wz = xzw + (PP + k) * OUT_UNITS + p * RR;
        const float* __restrict__ hb = xzb + p * RR;
        v2f h[8];
        #pragma unroll
        for (int r = 0; r < 8; ++r) {
            v2f hv = xv * wx[r] + hb[r];
            hv = zv * wz[r] + hv;
            h[r] = __builtin_elementwise_max(hv, zero);
        }

        const float* __restrict__ w1p = pw1 + p * (RR * PHH);
        const float* __restrict__ b1p = pb1 + p * PHH;
        v2f tv[16];
        #pragma unroll
        for (int j = 0; j < 16; ++j) { v2f b = {b1p[j], b1p[j]}; tv[j] = b; }
        #pragma unroll
        for (int r = 0; r < 8; ++r) {
            #pragma unroll
            for (int j = 0; j < 16; ++j)
                tv[j] = h[r] * w1p[r*16 + j] + tv[j];
        }
        const float* __restrict__ w2p = pw2 + p * PHH;
        #pragma unroll
        for (int j = 0; j < 16; j += 4) {
            acc0 = __builtin_elementwise_max(tv[j+0], zero) * w2p[j+0] + acc0;
            acc1 = __builtin_elementwise_max(tv[j+1], zero) * w2p[j+1] + acc1;
            acc2 = __builtin_elementwise_max(tv[j+2], zero) * w2p[j+2] + acc2;
            acc3 = __builtin_elementwise_max(tv[j+3], zero) * w2p[j+3] + acc3;
        }
    }
    v2f tot = (acc0 + acc1) + (acc2 + acc3);
    atomicAdd(out + b0 + 2*lane,     tot.x);
    atomicAdd(out + b0 + 2*lane + 1, tot.y);
}

extern "C" void kernel_launch(void* const* d_in, const int* in_sizes, int n_in,
                              void* d_out, int out_size, void* d_ws, size_t ws_size,
                              hipStream_t stream) {
    const float* x   = (const float*)d_in[0];
    const float* z   = (const float*)d_in[1];
    const float* xw1 = (const float*)d_in[2];
    const float* xb1 = (const float*)d_in[3];
    const float* xw2 = (const float*)d_in[4];
    const float* xb2 = (const float*)d_in[5];
    const float* xw3 = (const float*)d_in[6];
    const float* xb3 = (const float*)d_in[7];
    const float* zw1 = (const float*)d_in[8];
    const float* zb1 = (const float*)d_in[9];
    const float* zw2 = (const float*)d_in[10];
    const float* zb2 = (const float*)d_in[11];
    const float* zw3 = (const float*)d_in[12];
    const float* zb3 = (const float*)d_in[13];
    const float* xzw = (const float*)d_in[14];
    const float* xzb = (const float*)d_in[15];
    const float* pw1 = (const float*)d_in[16];
    const float* pb1 = (const float*)d_in[17];
    const float* pw2 = (const float*)d_in[18];
    float* out = (float*)d_out;

    zero_out_k<<<(out_size + 255) / 256, 256, 0, stream>>>(out, out_size);

    main_mlps_k<<<dim3(B_TOT / 64, 2, 2), 256, 0, stream>>>(
        x, z, xw1, xb1, xw2, xb2, xw3, xb3,
        zw1, zb1, zw2, zb2, zw3, zb3, out);

    interact_k<<<dim3(B_TOT / 128, PAIRS / 64), 256, 0, stream>>>(
        x, z, xzw, xzb, pw1, pb1, pw2, out);
}

// Round 3
// 178.291 us; speedup vs baseline: 1.0106x; 1.0029x over previous
//
#include <hip/hip_runtime.h>

#define B_TOT 8192
#define PP 32
#define QQ 32
#define RR 8
#define H1 128
#define H2 64
#define PHH 16
#define PAIRS 1024
#define OUT_UNITS 8192

typedef float v2f  __attribute__((ext_vector_type(2)));
typedef float f32x16 __attribute__((ext_vector_type(16)));
typedef short s16x8  __attribute__((ext_vector_type(8)));

union FragU { s16x8 v; unsigned int u[4]; };

// pack hi16(lo),hi16(hi) -> one dword (bf16 truncation), element 2d = lo
__device__ inline unsigned int pack_bf16(float lo, float hi) {
    return __builtin_amdgcn_perm(__float_as_uint(hi), __float_as_uint(lo), 0x07060302u);
}

// ---------------------------------------------------------------------------
// Main-effect MLPs, fused for both {x,z}: grid 128 blocks x 64 batches.
// Writes out[b] = out_x + out_z (initializes d_out; interact_k adds on top).
__global__ __launch_bounds__(256) void main_mlps_k(
    const float* __restrict__ x, const float* __restrict__ z,
    const float* __restrict__ xw1, const float* __restrict__ xb1,
    const float* __restrict__ xw2, const float* __restrict__ xb2,
    const float* __restrict__ xw3, const float* __restrict__ xb3,
    const float* __restrict__ zw1, const float* __restrict__ zb1,
    const float* __restrict__ zw2, const float* __restrict__ zb2,
    const float* __restrict__ zw3, const float* __restrict__ zb3,
    float* __restrict__ out)
{
    __shared__ float inT[32][65];    // [m][b]
    __shared__ float h1T[128][65];   // [j][b]
    __shared__ float red[4][64];

    const int t    = threadIdx.x;
    const int w    = __builtin_amdgcn_readfirstlane(t >> 6);
    const int lane = t & 63;
    const int b0   = blockIdx.x * 64;
    const v2f zero = {0.f, 0.f};

    float psum = 0.f;

    for (int which = 0; which < 2; ++which) {
        const float* in = which ? z   : x;
        const float* w1 = which ? zw1 : xw1;
        const float* b1 = which ? zb1 : xb1;
        const float* w2 = which ? zw2 : xw2;
        const float* b2 = which ? zb2 : xb2;
        const float* w3 = which ? zw3 : xw3;

        __syncthreads();   // protect LDS reuse across which iterations
        const float4* src = reinterpret_cast<const float4*>(in + (size_t)b0 * 32);
        #pragma unroll
        for (int it = 0; it < 2; ++it) {
            int fi = t + it * 256;            // 512 float4 total
            float4 v = src[fi];
            int bb = fi >> 3;
            int m  = (fi & 7) * 4;
            inT[m][bb] = v.x; inT[m+1][bb] = v.y; inT[m+2][bb] = v.z; inT[m+3][bb] = v.w;
        }
        __syncthreads();

        // phase A: h1 j-slice [32w, 32w+32), lane = b
        v2f h1[16];
        const v2f* b1v = reinterpret_cast<const v2f*>(b1 + w * 32);
        #pragma unroll
        for (int jj = 0; jj < 16; ++jj) h1[jj] = b1v[jj];
        #pragma unroll 4
        for (int m = 0; m < 32; ++m) {
            float xv = inT[m][lane];
            const v2f* w1v = reinterpret_cast<const v2f*>(w1 + m * H1 + w * 32);
            #pragma unroll
            for (int jj = 0; jj < 16; ++jj)
                h1[jj] = xv * w1v[jj] + h1[jj];
        }
        #pragma unroll
        for (int jj = 0; jj < 16; ++jj) {
            v2f r = __builtin_elementwise_max(h1[jj], zero);
            h1T[w*32 + 2*jj    ][lane] = r.x;
            h1T[w*32 + 2*jj + 1][lane] = r.y;
        }
        __syncthreads();

        // phase B: two h2 slices per wave: n0a = 8w, n0b = 32 + 8w
        const int n0a = w * 8;
        const int n0b = 32 + w * 8;
        const v2f* b2a = reinterpret_cast<const v2f*>(b2 + n0a);
        const v2f* b2b = reinterpret_cast<const v2f*>(b2 + n0b);
        v2f h2a[4], h2b[4];
        #pragma unroll
        for (int n = 0; n < 4; ++n) { h2a[n] = b2a[n]; h2b[n] = b2b[n]; }
        #pragma unroll 4
        for (int m = 0; m < 128; ++m) {
            float hv = h1T[m][lane];
            const v2f* w2a = reinterpret_cast<const v2f*>(w2 + m * H2 + n0a);
            const v2f* w2b = reinterpret_cast<const v2f*>(w2 + m * H2 + n0b);
            #pragma unroll
            for (int n = 0; n < 4; ++n) {
                h2a[n] = hv * w2a[n] + h2a[n];
                h2b[n] = hv * w2b[n] + h2b[n];
            }
        }
        const v2f* w3a = reinterpret_cast<const v2f*>(w3 + n0a);
        const v2f* w3b = reinterpret_cast<const v2f*>(w3 + n0b);
        v2f pv = zero;
        #pragma unroll
        for (int n = 0; n < 4; ++n) {
            pv = __builtin_elementwise_max(h2a[n], zero) * w3a[n] + pv;
            pv = __builtin_elementwise_max(h2b[n], zero) * w3b[n] + pv;
        }
        red[w][lane] = pv.x + pv.y;
        __syncthreads();
        if (w == 0)
            psum += red[0][lane] + red[1][lane] + red[2][lane] + red[3][lane];
    }
    if (w == 0)
        out[b0 + lane] = psum + xb3[0] + zb3[0];
}

// ---------------------------------------------------------------------------
// Interaction via MFMA 32x32x16 bf16 (K = 2 pairs x 8r, N = 2 pairs x 16j,
// block-diagonal B -> 2x padding). Grid (64 batch-tiles of 128, 64 pp-groups
// of 8). Each wave: 32 batches, loops 8 pair-pairs, fp32 acc[16] carried.
__global__ __launch_bounds__(256) void interact_k(
    const float* __restrict__ x, const float* __restrict__ z,
    const float* __restrict__ xzw, const float* __restrict__ xzb,
    const float* __restrict__ pw1, const float* __restrict__ pb1,
    const float* __restrict__ pw2, float* __restrict__ out)
{
    __shared__ float zT[16][128];     // [k - k0][b_local]
    __shared__ float red[4][32][34];  // [wave][row][col], pad 34 (b64-aligned)

    const int t    = threadIdx.x;
    const int w    = t >> 6;
    const int lane = t & 63;
    const int m    = lane & 31;       // batch row within wave / C-D column
    const int kh   = lane >> 5;       // A/B k-half = lane's pair selector
    const int col  = m;               // B/C/D column = lane&31
    const int jj   = col & 15;        // j within the column's pair
    const int cph  = col >> 4;        // column's pair selector
    const int b0   = blockIdx.x * 128;
    const int y    = blockIdx.y;      // pp-group
    const int pp0  = y * 8;
    const int i_x  = (y * 16) >> 5;   // x-feature, constant per block
    const int k0   = (y & 1) * 16;    // z-feature base for this block

    // stage zT: 128 batches x 16 z-features (transposed)
    {
        int row = t >> 1;
        int c8  = (t & 1) * 8;
        const float* src = z + (size_t)(b0 + row) * 32 + k0 + c8;
        float4 a4 = *reinterpret_cast<const float4*>(src);
        float4 b4 = *reinterpret_cast<const float4*>(src + 4);
        zT[c8+0][row] = a4.x; zT[c8+1][row] = a4.y; zT[c8+2][row] = a4.z; zT[c8+3][row] = a4.w;
        zT[c8+4][row] = b4.x; zT[c8+5][row] = b4.y; zT[c8+6][row] = b4.z; zT[c8+7][row] = b4.w;
    }
    const int b_local = w * 32 + m;
    const float xv = x[(size_t)(b0 + b_local) * 32 + i_x];
    __syncthreads();

    f32x16 acc, zeroC;
    #pragma unroll
    for (int r = 0; r < 16; ++r) { acc[r] = 0.f; zeroC[r] = 0.f; }

    const bool realB = (kh == cph);   // else this lane's B-frag is the zero block

    #pragma unroll 2
    for (int kk = 0; kk < 8; ++kk) {
        const int pp = pp0 + kk;
        const int pA = 2 * pp + kh;       // lane's pair (A operand / h)
        const int pB = 2 * pp + cph;      // column's pair (B operand / w2 / pb1)
        const int zrow = 2 * kk + kh;     // = (pA & 31) - k0

        const float zv = zT[zrow][b_local];

        const float4* wxp = reinterpret_cast<const float4*>(xzw + (size_t)i_x * OUT_UNITS + pA * 8);
        const float4* wzp = reinterpret_cast<const float4*>(xzw + (size_t)(32 + (2*pp + kh - (y&1)*16 + k0 - k0 + ((2*pp+kh)&31))) * 0 + ((size_t)(32 + ((2*pp+kh) & 31))) * OUT_UNITS + pA * 8);
        const float4* hbp = reinterpret_cast<const float4*>(xzb + pA * 8);
        float4 wx0 = wxp[0], wx1 = wxp[1];
        float4 wz0 = wzp[0], wz1 = wzp[1];
        float4 hb0 = hbp[0], hb1 = hbp[1];

        float h[8];
        h[0] = fmaxf(fmaf(xv, wx0.x, fmaf(zv, wz0.x, hb0.x)), 0.f);
        h[1] = fmaxf(fmaf(xv, wx0.y, fmaf(zv, wz0.y, hb0.y)), 0.f);
        h[2] = fmaxf(fmaf(xv, wx0.z, fmaf(zv, wz0.z, hb0.z)), 0.f);
        h[3] = fmaxf(fmaf(xv, wx0.w, fmaf(zv, wz0.w, hb0.w)), 0.f);
        h[4] = fmaxf(fmaf(xv, wx1.x, fmaf(zv, wz1.x, hb1.x)), 0.f);
        h[5] = fmaxf(fmaf(xv, wx1.y, fmaf(zv, wz1.y, hb1.y)), 0.f);
        h[6] = fmaxf(fmaf(xv, wx1.z, fmaf(zv, wz1.z, hb1.z)), 0.f);
        h[7] = fmaxf(fmaf(xv, wx1.w, fmaf(zv, wz1.w, hb1.w)), 0.f);

        FragU a;
        a.u[0] = pack_bf16(h[0], h[1]);
        a.u[1] = pack_bf16(h[2], h[3]);
        a.u[2] = pack_bf16(h[4], h[5]);
        a.u[3] = pack_bf16(h[6], h[7]);

        // B-frag: pw1[pB][i][jj], i = 0..7 (k = kh*8 + i -> r = i when realB)
        const float* bw = pw1 + (size_t)pB * 128 + jj;
        float bw0 = bw[0],  bw1 = bw[16], bw2 = bw[32],  bw3 = bw[48];
        float bw4 = bw[64], bw5 = bw[80], bw6 = bw[96],  bw7 = bw[112];
        FragU bf;
        bf.u[0] = realB ? pack_bf16(bw0, bw1) : 0u;
        bf.u[1] = realB ? pack_bf16(bw2, bw3) : 0u;
        bf.u[2] = realB ? pack_bf16(bw4, bw5) : 0u;
        bf.u[3] = realB ? pack_bf16(bw6, bw7) : 0u;

        const float w2v = pw2[pB * PHH + jj];
        const float pbv = pb1[pB * PHH + jj];

        f32x16 d = __builtin_amdgcn_mfma_f32_32x32x16_bf16(a.v, bf.v, zeroC, 0, 0, 0);

        #pragma unroll
        for (int r = 0; r < 16; ++r) {
            float tv = d[r] + pbv;
            acc[r] = fmaf(fmaxf(tv, 0.f), w2v, acc[r]);
        }
    }

    // per-wave column reduction: row = (reg&3) + 8*(reg>>2) + 4*kh
    #pragma unroll
    for (int r = 0; r < 16; ++r) {
        int row = (r & 3) + 8 * (r >> 2) + 4 * kh;
        red[w][row][col] = acc[r];
    }
    __syncthreads();
    if (t < 128) {
        int ww = t >> 5, row = t & 31;
        const float* rr = &red[ww][row][0];
        float s = 0.f;
        #pragma unroll
        for (int c = 0; c < 32; ++c) s += rr[c];
        atomicAdd(out + b0 + ww * 32 + row, s);
    }
}

extern "C" void kernel_launch(void* const* d_in, const int* in_sizes, int n_in,
                              void* d_out, int out_size, void* d_ws, size_t ws_size,
                              hipStream_t stream) {
    const float* x   = (const float*)d_in[0];
    const float* z   = (const float*)d_in[1];
    const float* xw1 = (const float*)d_in[2];
    const float* xb1 = (const float*)d_in[3];
    const float* xw2 = (const float*)d_in[4];
    const float* xb2 = (const float*)d_in[5];
    const float* xw3 = (const float*)d_in[6];
    const float* xb3 = (const float*)d_in[7];
    const float* zw1 = (const float*)d_in[8];
    const float* zb1 = (const float*)d_in[9];
    const float* zw2 = (const float*)d_in[10];
    const float* zb2 = (const float*)d_in[11];
    const float* zw3 = (const float*)d_in[12];
    const float* zb3 = (const float*)d_in[13];
    const float* xzw = (const float*)d_in[14];
    const float* xzb = (const float*)d_in[15];
    const float* pw1 = (const float*)d_in[16];
    const float* pb1 = (const float*)d_in[17];
    const float* pw2 = (const float*)d_in[18];
    float* out = (float*)d_out;

    // main_mlps initializes out (plain store), interact accumulates on top.
    main_mlps_k<<<dim3(B_TOT / 64), 256, 0, stream>>>(
        x, z, xw1, xb1, xw2, xb2, xw3, xb3,
        zw1, zb1, zw2, zb2, zw3, zb3, out);

    interact_k<<<dim3(B_TOT / 128, 64), 256, 0, stream>>>(
        x, z, xzw, xzb, pw1, pb1, pw2, out);
}

// Round 4
// 161.103 us; speedup vs baseline: 1.1184x; 1.1067x over previous
//
#include <hip/hip_runtime.h>

#define B_TOT 8192
#define PP 32
#define QQ 32
#define RR 8
#define H1 128
#define H2 64
#define PHH 16
#define PAIRS 1024
#define OUT_UNITS 8192

typedef float f32x16 __attribute__((ext_vector_type(16)));
typedef short s16x8  __attribute__((ext_vector_type(8)));

union FragU { s16x8 v; unsigned int u[4]; };

// pack hi16(lo),hi16(hi) -> one dword (bf16 truncation), element 2*d = lo
__device__ inline unsigned int pack_bf16(float lo, float hi) {
    return __builtin_amdgcn_perm(__float_as_uint(hi), __float_as_uint(lo), 0x07060302u);
}

__global__ void zero_out_k(float* __restrict__ out, int n) {
    int i = blockIdx.x * blockDim.x + threadIdx.x;
    if (i < n) out[i] = 0.f;
}

// Main-effect MLPs: grid (btile=128, hf=2, which=2) = 512 blocks, 4 waves.
// lane = batch element. Phase A: wave computes a 32-neuron h1 slice for 64
// b's; phase B: 8-neuron h2 slice from LDS. Weights wave-uniform -> s_load.
// (R3 lesson: do NOT fuse — 128 blocks leaves half the CUs idle.)
__global__ __launch_bounds__(256) void main_mlps_k(
    const float* __restrict__ x, const float* __restrict__ z,
    const float* __restrict__ xw1, const float* __restrict__ xb1,
    const float* __restrict__ xw2, const float* __restrict__ xb2,
    const float* __restrict__ xw3, const float* __restrict__ xb3,
    const float* __restrict__ zw1, const float* __restrict__ zb1,
    const float* __restrict__ zw2, const float* __restrict__ zb2,
    const float* __restrict__ zw3, const float* __restrict__ zb3,
    float* __restrict__ out)
{
    const int btile = blockIdx.x;
    const int hf    = blockIdx.y;
    const int which = blockIdx.z;
    const float* in = which ? z   : x;
    const float* w1 = which ? zw1 : xw1;
    const float* b1 = which ? zb1 : xb1;
    const float* w2 = which ? zw2 : xw2;
    const float* b2 = which ? zb2 : xb2;
    const float* w3 = which ? zw3 : xw3;
    const float* b3 = which ? zb3 : xb3;

    __shared__ float inT[32][65];    // [m][b] transposed input tile
    __shared__ float h1T[128][65];   // [j][b]

    const int t    = threadIdx.x;
    const int w    = __builtin_amdgcn_readfirstlane(t >> 6);
    const int lane = t & 63;
    const int b0   = btile * 64;

    const float4* src = reinterpret_cast<const float4*>(in + (size_t)b0 * 32);
    #pragma unroll
    for (int it = 0; it < 2; ++it) {
        int fi = t + it * 256;            // 512 float4 total
        float4 v = src[fi];
        int bb = fi >> 3;
        int m  = (fi & 7) * 4;
        inT[m][bb] = v.x; inT[m+1][bb] = v.y; inT[m+2][bb] = v.z; inT[m+3][bb] = v.w;
    }
    __syncthreads();

    // phase A: h1[j] for j in [32w, 32w+32), all 64 b's (lane = b)
    float h1[32];
    #pragma unroll
    for (int j = 0; j < 32; ++j) h1[j] = b1[w*32 + j];
    #pragma unroll 4
    for (int m = 0; m < 32; ++m) {
        float xv = inT[m][lane];
        #pragma unroll
        for (int j = 0; j < 32; ++j)
            h1[j] = fmaf(xv, w1[m*H1 + w*32 + j], h1[j]);
    }
    #pragma unroll
    for (int j = 0; j < 32; ++j)
        h1T[w*32 + j][lane] = fmaxf(h1[j], 0.f);
    __syncthreads();

    // phase B: h2[n] for n in [hf*32 + 8w, +8)
    const int n0 = __builtin_amdgcn_readfirstlane(hf*32 + w*8);
    float h2[8];
    #pragma unroll
    for (int n = 0; n < 8; ++n) h2[n] = b2[n0 + n];
    #pragma unroll 4
    for (int m = 0; m < 128; ++m) {
        float hv = h1T[m][lane];
        #pragma unroll
        for (int n = 0; n < 8; ++n)
            h2[n] = fmaf(hv, w2[m*H2 + n0 + n], h2[n]);
    }
    float p = 0.f;
    #pragma unroll
    for (int n = 0; n < 8; ++n)
        p = fmaf(fmaxf(h2[n], 0.f), w3[n0 + n], p);
    if (hf == 0 && w == 0) p += b3[0];
    atomicAdd(out + b0 + lane, p);
}

// Interaction via MFMA 32x32x16 bf16 (K = 2 pairs x 8r, N = 2 pairs x 16j,
// block-diagonal B -> 2x padding). Grid (64 batch-tiles of 128, 64 pp-groups
// of 8). Each wave: 32 batches, loops 8 pair-pairs, fp32 acc[16] carried.
__global__ __launch_bounds__(256) void interact_k(
    const float* __restrict__ x, const float* __restrict__ z,
    const float* __restrict__ xzw, const float* __restrict__ xzb,
    const float* __restrict__ pw1, const float* __restrict__ pb1,
    const float* __restrict__ pw2, float* __restrict__ out)
{
    __shared__ float zT[16][128];     // [k - k0][b_local]
    __shared__ float red[4][32][34];  // [wave][row][col]

    const int t    = threadIdx.x;
    const int w    = t >> 6;
    const int lane = t & 63;
    const int m    = lane & 31;       // batch row within wave / C-D column
    const int kh   = lane >> 5;       // A/B k-half = lane's pair selector
    const int col  = m;               // B/C/D column = lane&31
    const int jj   = col & 15;        // j within the column's pair
    const int cph  = col >> 4;        // column's pair selector
    const int b0   = blockIdx.x * 128;
    const int y    = blockIdx.y;      // pp-group
    const int pp0  = y * 8;
    const int i_x  = y >> 1;          // x-feature, constant per block
    const int k0   = (y & 1) * 16;    // z-feature base for this block

    // stage zT: 128 batches x 16 z-features (transposed)
    {
        int row = t >> 1;
        int c8  = (t & 1) * 8;
        const float* src = z + (size_t)(b0 + row) * 32 + k0 + c8;
        float4 a4 = *reinterpret_cast<const float4*>(src);
        float4 b4 = *reinterpret_cast<const float4*>(src + 4);
        zT[c8+0][row] = a4.x; zT[c8+1][row] = a4.y; zT[c8+2][row] = a4.z; zT[c8+3][row] = a4.w;
        zT[c8+4][row] = b4.x; zT[c8+5][row] = b4.y; zT[c8+6][row] = b4.z; zT[c8+7][row] = b4.w;
    }
    const int b_local = w * 32 + m;
    const float xv = x[(size_t)(b0 + b_local) * 32 + i_x];
    __syncthreads();

    f32x16 acc, zeroC;
    #pragma unroll
    for (int r = 0; r < 16; ++r) { acc[r] = 0.f; zeroC[r] = 0.f; }

    const bool realB = (kh == cph);   // else this lane's B-frag is the zero block

    #pragma unroll 2
    for (int kk = 0; kk < 8; ++kk) {
        const int pp = pp0 + kk;
        const int pA = 2 * pp + kh;       // lane's pair (A operand / h)
        const int pB = 2 * pp + cph;      // column's pair (B operand / w2 / pb1)
        const int zrow = 2 * kk + kh;     // = (pA & 31) - k0

        const float zv = zT[zrow][b_local];

        const float4* wxp = reinterpret_cast<const float4*>(xzw + (size_t)i_x * OUT_UNITS + pA * 8);
        const float4* wzp = reinterpret_cast<const float4*>(xzw + (size_t)(32 + (pA & 31)) * OUT_UNITS + pA * 8);
        const float4* hbp = reinterpret_cast<const float4*>(xzb + pA * 8);
        float4 wx0 = wxp[0], wx1 = wxp[1];
        float4 wz0 = wzp[0], wz1 = wzp[1];
        float4 hb0 = hbp[0], hb1 = hbp[1];

        float h[8];
        h[0] = fmaxf(fmaf(xv, wx0.x, fmaf(zv, wz0.x, hb0.x)), 0.f);
        h[1] = fmaxf(fmaf(xv, wx0.y, fmaf(zv, wz0.y, hb0.y)), 0.f);
        h[2] = fmaxf(fmaf(xv, wx0.z, fmaf(zv, wz0.z, hb0.z)), 0.f);
        h[3] = fmaxf(fmaf(xv, wx0.w, fmaf(zv, wz0.w, hb0.w)), 0.f);
        h[4] = fmaxf(fmaf(xv, wx1.x, fmaf(zv, wz1.x, hb1.x)), 0.f);
        h[5] = fmaxf(fmaf(xv, wx1.y, fmaf(zv, wz1.y, hb1.y)), 0.f);
        h[6] = fmaxf(fmaf(xv, wx1.z, fmaf(zv, wz1.z, hb1.z)), 0.f);
        h[7] = fmaxf(fmaf(xv, wx1.w, fmaf(zv, wz1.w, hb1.w)), 0.f);

        FragU a;
        a.u[0] = pack_bf16(h[0], h[1]);
        a.u[1] = pack_bf16(h[2], h[3]);
        a.u[2] = pack_bf16(h[4], h[5]);
        a.u[3] = pack_bf16(h[6], h[7]);

        // B-frag: pw1[pB][i][jj], i = 0..7
        const float* bw = pw1 + (size_t)pB * 128 + jj;
        float bw0 = bw[0],  bw1 = bw[16], bw2 = bw[32],  bw3 = bw[48];
        float bw4 = bw[64], bw5 = bw[80], bw6 = bw[96],  bw7 = bw[112];
        FragU bf;
        bf.u[0] = realB ? pack_bf16(bw0, bw1) : 0u;
        bf.u[1] = realB ? pack_bf16(bw2, bw3) : 0u;
        bf.u[2] = realB ? pack_bf16(bw4, bw5) : 0u;
        bf.u[3] = realB ? pack_bf16(bw6, bw7) : 0u;

        const float w2v = pw2[pB * PHH + jj];
        const float pbv = pb1[pB * PHH + jj];

        f32x16 d = __builtin_amdgcn_mfma_f32_32x32x16_bf16(a.v, bf.v, zeroC, 0, 0, 0);

        #pragma unroll
        for (int r = 0; r < 16; ++r) {
            float tv = d[r] + pbv;
            acc[r] = fmaf(fmaxf(tv, 0.f), w2v, acc[r]);
        }
    }

    // per-wave column reduction: row = (reg&3) + 8*(reg>>2) + 4*kh
    #pragma unroll
    for (int r = 0; r < 16; ++r) {
        int row = (r & 3) + 8 * (r >> 2) + 4 * kh;
        red[w][row][col] = acc[r];
    }
    __syncthreads();
    if (t < 128) {
        int ww = t >> 5, row = t & 31;
        const float* rr = &red[ww][row][0];
        float s = 0.f;
        #pragma unroll
        for (int c = 0; c < 32; ++c) s += rr[c];
        atomicAdd(out + b0 + ww * 32 + row, s);
    }
}

extern "C" void kernel_launch(void* const* d_in, const int* in_sizes, int n_in,
                              void* d_out, int out_size, void* d_ws, size_t ws_size,
                              hipStream_t stream) {
    const float* x   = (const float*)d_in[0];
    const float* z   = (const float*)d_in[1];
    const float* xw1 = (const float*)d_in[2];
    const float* xb1 = (const float*)d_in[3];
    const float* xw2 = (const float*)d_in[4];
    const float* xb2 = (const float*)d_in[5];
    const float* xw3 = (const float*)d_in[6];
    const float* xb3 = (const float*)d_in[7];
    const float* zw1 = (const float*)d_in[8];
    const float* zb1 = (const float*)d_in[9];
    const float* zw2 = (const float*)d_in[10];
    const float* zb2 = (const float*)d_in[11];
    const float* zw3 = (const float*)d_in[12];
    const float* zb3 = (const float*)d_in[13];
    const float* xzw = (const float*)d_in[14];
    const float* xzb = (const float*)d_in[15];
    const float* pw1 = (const float*)d_in[16];
    const float* pb1 = (const float*)d_in[17];
    const float* pw2 = (const float*)d_in[18];
    float* out = (float*)d_out;

    zero_out_k<<<(out_size + 255) / 256, 256, 0, stream>>>(out, out_size);

    main_mlps_k<<<dim3(B_TOT / 64, 2, 2), 256, 0, stream>>>(
        x, z, xw1, xb1, xw2, xb2, xw3, xb3,
        zw1, zb1, zw2, zb2, zw3, zb3, out);

    interact_k<<<dim3(B_TOT / 128, 64), 256, 0, stream>>>(
        x, z, xzw, xzb, pw1, pb1, pw2, out);
}

// Round 5
// 140.976 us; speedup vs baseline: 1.2781x; 1.1428x over previous
//
#include <hip/hip_runtime.h>

#define B_TOT 8192
#define PP 32
#define QQ 32
#define RR 8
#define H1 128
#define H2 64
#define PHH 16
#define PAIRS 1024
#define OUT_UNITS 8192

typedef float f32x16 __attribute__((ext_vector_type(16)));
typedef short s16x8  __attribute__((ext_vector_type(8)));

union FragU { s16x8 v; unsigned int u[4]; };

// pack hi16(lo),hi16(hi) -> one dword (bf16 truncation), element 2*d = lo
__device__ inline unsigned int pack_bf16(float lo, float hi) {
    return __builtin_amdgcn_perm(__float_as_uint(hi), __float_as_uint(lo), 0x07060302u);
}

__global__ void zero_out_k(float* __restrict__ out, int n) {
    int i = blockIdx.x * blockDim.x + threadIdx.x;
    if (i < n) out[i] = 0.f;
}

// Main-effect MLPs: grid (btile=128, hf=2, which=2) = 512 blocks, 4 waves.
// (R3 lesson: do NOT fuse to 128 blocks — half the CUs idle.)
__global__ __launch_bounds__(256) void main_mlps_k(
    const float* __restrict__ x, const float* __restrict__ z,
    const float* __restrict__ xw1, const float* __restrict__ xb1,
    const float* __restrict__ xw2, const float* __restrict__ xb2,
    const float* __restrict__ xw3, const float* __restrict__ xb3,
    const float* __restrict__ zw1, const float* __restrict__ zb1,
    const float* __restrict__ zw2, const float* __restrict__ zb2,
    const float* __restrict__ zw3, const float* __restrict__ zb3,
    float* __restrict__ out)
{
    const int btile = blockIdx.x;
    const int hf    = blockIdx.y;
    const int which = blockIdx.z;
    const float* in = which ? z   : x;
    const float* w1 = which ? zw1 : xw1;
    const float* b1 = which ? zb1 : xb1;
    const float* w2 = which ? zw2 : xw2;
    const float* b2 = which ? zb2 : xb2;
    const float* w3 = which ? zw3 : xw3;
    const float* b3 = which ? zb3 : xb3;

    __shared__ float inT[32][65];
    __shared__ float h1T[128][65];

    const int t    = threadIdx.x;
    const int w    = __builtin_amdgcn_readfirstlane(t >> 6);
    const int lane = t & 63;
    const int b0   = btile * 64;

    const float4* src = reinterpret_cast<const float4*>(in + (size_t)b0 * 32);
    #pragma unroll
    for (int it = 0; it < 2; ++it) {
        int fi = t + it * 256;
        float4 v = src[fi];
        int bb = fi >> 3;
        int m  = (fi & 7) * 4;
        inT[m][bb] = v.x; inT[m+1][bb] = v.y; inT[m+2][bb] = v.z; inT[m+3][bb] = v.w;
    }
    __syncthreads();

    float h1[32];
    #pragma unroll
    for (int j = 0; j < 32; ++j) h1[j] = b1[w*32 + j];
    #pragma unroll 4
    for (int m = 0; m < 32; ++m) {
        float xv = inT[m][lane];
        #pragma unroll
        for (int j = 0; j < 32; ++j)
            h1[j] = fmaf(xv, w1[m*H1 + w*32 + j], h1[j]);
    }
    #pragma unroll
    for (int j = 0; j < 32; ++j)
        h1T[w*32 + j][lane] = fmaxf(h1[j], 0.f);
    __syncthreads();

    const int n0 = __builtin_amdgcn_readfirstlane(hf*32 + w*8);
    float h2[8];
    #pragma unroll
    for (int n = 0; n < 8; ++n) h2[n] = b2[n0 + n];
    #pragma unroll 4
    for (int m = 0; m < 128; ++m) {
        float hv = h1T[m][lane];
        #pragma unroll
        for (int n = 0; n < 8; ++n)
            h2[n] = fmaf(hv, w2[m*H2 + n0 + n], h2[n]);
    }
    float p = 0.f;
    #pragma unroll
    for (int n = 0; n < 8; ++n)
        p = fmaf(fmaxf(h2[n], 0.f), w3[n0 + n], p);
    if (hf == 0 && w == 0) p += b3[0];
    atomicAdd(out + b0 + lane, p);
}

// Interaction v2: MFMA 32x32x16 bf16, grid (64 b-tiles of 128, 64 pp-groups).
// Wave = 64 batches (2 MFMA tiles sharing B-frag) x 4 pps. All weights staged
// in LDS once per block (pw1 pre-packed bf16). Phased LDS reduction.
__global__ __launch_bounds__(256, 3) void interact_k(
    const float* __restrict__ x, const float* __restrict__ z,
    const float* __restrict__ xzw, const float* __restrict__ xzb,
    const float* __restrict__ pw1, const float* __restrict__ pb1,
    const float* __restrict__ pw2, float* __restrict__ out)
{
    __shared__ float zT[16][128];            // 8 KB
    __shared__ float4 lwx[16][2];            // wx[pair][8]
    __shared__ float4 lwz[16][2];
    __shared__ float4 lhb[16][2];
    __shared__ unsigned lpw1[16][4][16];     // pre-packed bf16 pairs (rows 2u,2u+1)
    __shared__ float lpb[16][16];
    __shared__ float lpw2[16][16];
    __shared__ float red[128][33];           // 16.5 KB

    const int t     = threadIdx.x;
    const int w     = t >> 6;
    const int lane  = t & 63;
    const int m     = lane & 31;     // C/D column, batch row within tile
    const int kh    = lane >> 5;     // A k-half / pair selector
    const int jj    = m & 15;
    const int cph   = m >> 4;        // column's pair selector
    const int b0    = blockIdx.x * 128;
    const int y     = blockIdx.y;
    const int i_x   = y >> 1;        // shared x-feature of this block's 16 pairs
    const int k0    = (y & 1) * 16;  // z-feature base
    const int pair0 = y * 16;        // global pair index of local pair 0

    // ---- stage zT: 128 batches x 16 z-features (transposed) ----
    {
        int row = t >> 1;
        int c8  = (t & 1) * 8;
        const float* src = z + (size_t)(b0 + row) * 32 + k0 + c8;
        float4 a4 = *reinterpret_cast<const float4*>(src);
        float4 b4 = *reinterpret_cast<const float4*>(src + 4);
        zT[c8+0][row] = a4.x; zT[c8+1][row] = a4.y; zT[c8+2][row] = a4.z; zT[c8+3][row] = a4.w;
        zT[c8+4][row] = b4.x; zT[c8+5][row] = b4.y; zT[c8+6][row] = b4.z; zT[c8+7][row] = b4.w;
    }
    // ---- stage h-layer weights: lwx/lwz/lhb (128 dwords each, coalesced) ----
    if (t < 128) {
        int p = t >> 3, c = t & 7;
        int gp = pair0 + p;
        reinterpret_cast<float*>(lwx)[t] = xzw[(size_t)i_x * OUT_UNITS + gp*8 + c];
        reinterpret_cast<float*>(lwz)[t] = xzw[(size_t)(32 + k0 + p) * OUT_UNITS + gp*8 + c];
        reinterpret_cast<float*>(lhb)[t] = xzb[gp*8 + c];
    }
    // ---- stage pb1 / pw2 (256 dwords each, coalesced) ----
    {
        int p = t >> 4, j = t & 15;
        int gp = pair0 + p;
        lpb[p][j]  = pb1[gp*PHH + j];
        lpw2[p][j] = pw2[gp*PHH + j];
    }
    // ---- stage pw1 pre-packed to bf16 (1024 dwords) ----
    #pragma unroll
    for (int it = 0; it < 4; ++it) {
        int idx = t + it * 256;
        int p = idx >> 6, u = (idx >> 4) & 3, j = idx & 15;
        int gp = pair0 + p;
        float lo = pw1[(size_t)gp * 128 + (2*u)*16 + j];
        float hi = pw1[(size_t)gp * 128 + (2*u+1)*16 + j];
        lpw1[p][u][j] = pack_bf16(lo, hi);
    }

    const int bl  = (w & 1) * 64 + m;           // tile0 batch (local)
    const float xv0 = x[(size_t)(b0 + bl)      * 32 + i_x];
    const float xv1 = x[(size_t)(b0 + bl + 32) * 32 + i_x];
    __syncthreads();

    f32x16 acc0, acc1, zeroC;
    #pragma unroll
    for (int r = 0; r < 16; ++r) { acc0[r] = 0.f; acc1[r] = 0.f; zeroC[r] = 0.f; }

    const bool realB = (kh == cph);
    const int  ppl0  = (w >> 1) * 4;            // waves 0,1 -> pps 0-3; 2,3 -> 4-7

    #pragma unroll 2
    for (int kk = 0; kk < 4; ++kk) {
        const int ppl = ppl0 + kk;
        const int pAl = 2*ppl + kh;             // lane's local pair (A / h)
        const int pBl = 2*ppl + cph;            // column's local pair (B / pw2 / pb1)

        const float zv0 = zT[pAl][bl];
        const float zv1 = zT[pAl][bl + 32];
        const float4 wxa = lwx[pAl][0], wxb = lwx[pAl][1];
        const float4 wza = lwz[pAl][0], wzb = lwz[pAl][1];
        const float4 hba = lhb[pAl][0], hbb = lhb[pAl][1];

        float h0[8], h1[8];
        h0[0] = fmaxf(fmaf(xv0, wxa.x, fmaf(zv0, wza.x, hba.x)), 0.f);
        h0[1] = fmaxf(fmaf(xv0, wxa.y, fmaf(zv0, wza.y, hba.y)), 0.f);
        h0[2] = fmaxf(fmaf(xv0, wxa.z, fmaf(zv0, wza.z, hba.z)), 0.f);
        h0[3] = fmaxf(fmaf(xv0, wxa.w, fmaf(zv0, wza.w, hba.w)), 0.f);
        h0[4] = fmaxf(fmaf(xv0, wxb.x, fmaf(zv0, wzb.x, hbb.x)), 0.f);
        h0[5] = fmaxf(fmaf(xv0, wxb.y, fmaf(zv0, wzb.y, hbb.y)), 0.f);
        h0[6] = fmaxf(fmaf(xv0, wxb.z, fmaf(zv0, wzb.z, hbb.z)), 0.f);
        h0[7] = fmaxf(fmaf(xv0, wxb.w, fmaf(zv0, wzb.w, hbb.w)), 0.f);
        h1[0] = fmaxf(fmaf(xv1, wxa.x, fmaf(zv1, wza.x, hba.x)), 0.f);
        h1[1] = fmaxf(fmaf(xv1, wxa.y, fmaf(zv1, wza.y, hba.y)), 0.f);
        h1[2] = fmaxf(fmaf(xv1, wxa.z, fmaf(zv1, wza.z, hba.z)), 0.f);
        h1[3] = fmaxf(fmaf(xv1, wxa.w, fmaf(zv1, wza.w, hba.w)), 0.f);
        h1[4] = fmaxf(fmaf(xv1, wxb.x, fmaf(zv1, wzb.x, hbb.x)), 0.f);
        h1[5] = fmaxf(fmaf(xv1, wxb.y, fmaf(zv1, wzb.y, hbb.y)), 0.f);
        h1[6] = fmaxf(fmaf(xv1, wxb.z, fmaf(zv1, wzb.z, hbb.z)), 0.f);
        h1[7] = fmaxf(fmaf(xv1, wxb.w, fmaf(zv1, wzb.w, hbb.w)), 0.f);

        FragU a0, a1, bf;
        a0.u[0] = pack_bf16(h0[0], h0[1]);
        a0.u[1] = pack_bf16(h0[2], h0[3]);
        a0.u[2] = pack_bf16(h0[4], h0[5]);
        a0.u[3] = pack_bf16(h0[6], h0[7]);
        a1.u[0] = pack_bf16(h1[0], h1[1]);
        a1.u[1] = pack_bf16(h1[2], h1[3]);
        a1.u[2] = pack_bf16(h1[4], h1[5]);
        a1.u[3] = pack_bf16(h1[6], h1[7]);
        bf.u[0] = realB ? lpw1[pBl][0][jj] : 0u;
        bf.u[1] = realB ? lpw1[pBl][1][jj] : 0u;
        bf.u[2] = realB ? lpw1[pBl][2][jj] : 0u;
        bf.u[3] = realB ? lpw1[pBl][3][jj] : 0u;

        const float pbv = lpb[pBl][jj];
        const float w2v = lpw2[pBl][jj];

        f32x16 d0 = __builtin_amdgcn_mfma_f32_32x32x16_bf16(a0.v, bf.v, zeroC, 0, 0, 0);
        f32x16 d1 = __builtin_amdgcn_mfma_f32_32x32x16_bf16(a1.v, bf.v, zeroC, 0, 0, 0);

        #pragma unroll
        for (int r = 0; r < 16; ++r)
            acc0[r] = fmaf(fmaxf(d0[r] + pbv, 0.f), w2v, acc0[r]);
        #pragma unroll
        for (int r = 0; r < 16; ++r)
            acc1[r] = fmaf(fmaxf(d1[r] + pbv, 0.f), w2v, acc1[r]);
    }

    // ---- phased reduction: waves 0,1 write; waves 2,3 accumulate ----
    const int rb0 = (w & 1) * 64;
    if (w < 2) {
        #pragma unroll
        for (int r = 0; r < 16; ++r) {
            int rowf = (r & 3) + 8 * (r >> 2) + 4 * kh;
            red[rb0 + rowf][m]      = acc0[r];
            red[rb0 + 32 + rowf][m] = acc1[r];
        }
    }
    __syncthreads();
    if (w >= 2) {
        #pragma unroll
        for (int r = 0; r < 16; ++r) {
            int rowf = (r & 3) + 8 * (r >> 2) + 4 * kh;
            red[rb0 + rowf][m]      += acc0[r];
            red[rb0 + 32 + rowf][m] += acc1[r];
        }
    }
    __syncthreads();
    if (t < 128) {
        float s = 0.f;
        #pragma unroll
        for (int c = 0; c < 32; ++c) s += red[t][c];
        atomicAdd(out + b0 + t, s);
    }
}

extern "C" void kernel_launch(void* const* d_in, const int* in_sizes, int n_in,
                              void* d_out, int out_size, void* d_ws, size_t ws_size,
                              hipStream_t stream) {
    const float* x   = (const float*)d_in[0];
    const float* z   = (const float*)d_in[1];
    const float* xw1 = (const float*)d_in[2];
    const float* xb1 = (const float*)d_in[3];
    const float* xw2 = (const float*)d_in[4];
    const float* xb2 = (const float*)d_in[5];
    const float* xw3 = (const float*)d_in[6];
    const float* xb3 = (const float*)d_in[7];
    const float* zw1 = (const float*)d_in[8];
    const float* zb1 = (const float*)d_in[9];
    const float* zw2 = (const float*)d_in[10];
    const float* zb2 = (const float*)d_in[11];
    const float* zw3 = (const float*)d_in[12];
    const float* zb3 = (const float*)d_in[13];
    const float* xzw = (const float*)d_in[14];
    const float* xzb = (const float*)d_in[15];
    const float* pw1 = (const float*)d_in[16];
    const float* pb1 = (const float*)d_in[17];
    const float* pw2 = (const float*)d_in[18];
    float* out = (float*)d_out;

    zero_out_k<<<(out_size + 255) / 256, 256, 0, stream>>>(out, out_size);

    main_mlps_k<<<dim3(B_TOT / 64, 2, 2), 256, 0, stream>>>(
        x, z, xw1, xb1, xw2, xb2, xw3, xb3,
        zw1, zb1, zw2, zb2, zw3, zb3, out);

    interact_k<<<dim3(B_TOT / 128, 64), 256, 0, stream>>>(
        x, z, xzw, xzb, pw1, pb1, pw2, out);
}

// Round 6
// 137.371 us; speedup vs baseline: 1.3116x; 1.0262x over previous
//
#include <hip/hip_runtime.h>

#define B_TOT 8192
#define PP 32
#define QQ 32
#define RR 8
#define H1 128
#define H2 64
#define PHH 16
#define PAIRS 1024
#define OUT_UNITS 8192

#define NBLK_IA 4096   // interact-role blocks: (64 b-tiles of 128) x (64 pp-groups)
#define NBLK_MM 512    // main-role blocks: 128 btiles x 2 hf x 2 which

typedef float f32x16 __attribute__((ext_vector_type(16)));
typedef short s16x8  __attribute__((ext_vector_type(8)));

union FragU { s16x8 v; unsigned int u[4]; };

// pack hi16(lo),hi16(hi) -> one dword (bf16 truncation), element 2*d = lo
__device__ inline unsigned int pack_bf16(float lo, float hi) {
    return __builtin_amdgcn_perm(__float_as_uint(hi), __float_as_uint(lo), 0x07060302u);
}

union SharedU {
    struct {                       // interact role: 32 KB
        float zT[16][128];
        float4 lwx[16][2];
        float4 lwz[16][2];
        float4 lhb[16][2];
        unsigned lpw1[16][4][16];
        float lpb[16][16];
        float lpw2[16][16];
        float red[128][33];
    } ia;
    struct {                       // main role: 34.3 KB
        float h1T[128][65];
        float red2[4][64];
    } mm;
};

// Fused kernel. Blocks [0,4096): interaction via MFMA 32x32x16 bf16
// (wave = 64 batches = 2 tiles sharing B-frag, 4 pps each; pb1 folded into
// MFMA C operand). Blocks [4096,4608): main-effect MLPs (R3 lesson: keep
// 512 role-blocks — they co-run with interact blocks, hiding their latency).
__global__ __launch_bounds__(256, 4) void fused_k(
    const float* __restrict__ x, const float* __restrict__ z,
    const float* __restrict__ xw1, const float* __restrict__ xb1,
    const float* __restrict__ xw2, const float* __restrict__ xb2,
    const float* __restrict__ xw3, const float* __restrict__ xb3,
    const float* __restrict__ zw1, const float* __restrict__ zb1,
    const float* __restrict__ zw2, const float* __restrict__ zb2,
    const float* __restrict__ zw3, const float* __restrict__ zb3,
    const float* __restrict__ xzw, const float* __restrict__ xzb,
    const float* __restrict__ pw1, const float* __restrict__ pb1,
    const float* __restrict__ pw2, float* __restrict__ out)
{
    __shared__ SharedU sh;
    const int bid  = blockIdx.x;
    const int t    = threadIdx.x;
    const int w    = t >> 6;
    const int lane = t & 63;

    if (bid < NBLK_IA) {
        // ------------------------- interaction role -------------------------
        const int bx    = bid & 63;
        const int y     = bid >> 6;
        const int m     = lane & 31;     // batch row within tile
        const int kh    = lane >> 5;     // A k-half / pair selector
        const int jj    = m & 15;        // j within column's pair
        const int cph   = m >> 4;        // column's pair selector
        const int b0    = bx * 128;
        const int i_x   = y >> 1;        // shared x-feature of the 16 pairs
        const int k0    = (y & 1) * 16;  // z-feature base
        const int pair0 = y * 16;

        // stage zT: 128 batches x 16 z-features (transposed)
        {
            int row = t >> 1;
            int c8  = (t & 1) * 8;
            const float* src = z + (size_t)(b0 + row) * 32 + k0 + c8;
            float4 a4 = *reinterpret_cast<const float4*>(src);
            float4 b4 = *reinterpret_cast<const float4*>(src + 4);
            sh.ia.zT[c8+0][row] = a4.x; sh.ia.zT[c8+1][row] = a4.y;
            sh.ia.zT[c8+2][row] = a4.z; sh.ia.zT[c8+3][row] = a4.w;
            sh.ia.zT[c8+4][row] = b4.x; sh.ia.zT[c8+5][row] = b4.y;
            sh.ia.zT[c8+6][row] = b4.z; sh.ia.zT[c8+7][row] = b4.w;
        }
        // stage h-layer weights (coalesced)
        if (t < 128) {
            int p = t >> 3, c = t & 7;
            int gp = pair0 + p;
            reinterpret_cast<float*>(sh.ia.lwx)[t] = xzw[(size_t)i_x * OUT_UNITS + gp*8 + c];
            reinterpret_cast<float*>(sh.ia.lwz)[t] = xzw[(size_t)(32 + k0 + p) * OUT_UNITS + gp*8 + c];
            reinterpret_cast<float*>(sh.ia.lhb)[t] = xzb[gp*8 + c];
        }
        // stage pb1 / pw2
        {
            int p = t >> 4, j = t & 15;
            int gp = pair0 + p;
            sh.ia.lpb[p][j]  = pb1[gp*PHH + j];
            sh.ia.lpw2[p][j] = pw2[gp*PHH + j];
        }
        // stage pw1 pre-packed to bf16
        #pragma unroll
        for (int it = 0; it < 4; ++it) {
            int idx = t + it * 256;
            int p = idx >> 6, u = (idx >> 4) & 3, j = idx & 15;
            int gp = pair0 + p;
            float lo = pw1[(size_t)gp * 128 + (2*u)*16 + j];
            float hi = pw1[(size_t)gp * 128 + (2*u+1)*16 + j];
            sh.ia.lpw1[p][u][j] = pack_bf16(lo, hi);
        }

        const int bl = (w & 1) * 64 + m;
        const float xv0 = x[(size_t)(b0 + bl)      * 32 + i_x];
        const float xv1 = x[(size_t)(b0 + bl + 32) * 32 + i_x];
        __syncthreads();

        f32x16 acc0, acc1;
        #pragma unroll
        for (int r = 0; r < 16; ++r) { acc0[r] = 0.f; acc1[r] = 0.f; }

        const bool realB = (kh == cph);
        const int  ppl0  = (w >> 1) * 4;

        #pragma unroll 2
        for (int kk = 0; kk < 4; ++kk) {
            const int ppl = ppl0 + kk;
            const int pAl = 2*ppl + kh;
            const int pBl = 2*ppl + cph;

            const float zv0 = sh.ia.zT[pAl][bl];
            const float zv1 = sh.ia.zT[pAl][bl + 32];
            const float4 wxa = sh.ia.lwx[pAl][0], wxb = sh.ia.lwx[pAl][1];
            const float4 wza = sh.ia.lwz[pAl][0], wzb = sh.ia.lwz[pAl][1];
            const float4 hba = sh.ia.lhb[pAl][0], hbb = sh.ia.lhb[pAl][1];

            float h0[8], h1v[8];
            h0[0] = fmaxf(fmaf(xv0, wxa.x, fmaf(zv0, wza.x, hba.x)), 0.f);
            h0[1] = fmaxf(fmaf(xv0, wxa.y, fmaf(zv0, wza.y, hba.y)), 0.f);
            h0[2] = fmaxf(fmaf(xv0, wxa.z, fmaf(zv0, wza.z, hba.z)), 0.f);
            h0[3] = fmaxf(fmaf(xv0, wxa.w, fmaf(zv0, wza.w, hba.w)), 0.f);
            h0[4] = fmaxf(fmaf(xv0, wxb.x, fmaf(zv0, wzb.x, hbb.x)), 0.f);
            h0[5] = fmaxf(fmaf(xv0, wxb.y, fmaf(zv0, wzb.y, hbb.y)), 0.f);
            h0[6] = fmaxf(fmaf(xv0, wxb.z, fmaf(zv0, wzb.z, hbb.z)), 0.f);
            h0[7] = fmaxf(fmaf(xv0, wxb.w, fmaf(zv0, wzb.w, hbb.w)), 0.f);
            h1v[0] = fmaxf(fmaf(xv1, wxa.x, fmaf(zv1, wza.x, hba.x)), 0.f);
            h1v[1] = fmaxf(fmaf(xv1, wxa.y, fmaf(zv1, wza.y, hba.y)), 0.f);
            h1v[2] = fmaxf(fmaf(xv1, wxa.z, fmaf(zv1, wza.z, hba.z)), 0.f);
            h1v[3] = fmaxf(fmaf(xv1, wxa.w, fmaf(zv1, wza.w, hba.w)), 0.f);
            h1v[4] = fmaxf(fmaf(xv1, wxb.x, fmaf(zv1, wzb.x, hbb.x)), 0.f);
            h1v[5] = fmaxf(fmaf(xv1, wxb.y, fmaf(zv1, wzb.y, hbb.y)), 0.f);
            h1v[6] = fmaxf(fmaf(xv1, wxb.z, fmaf(zv1, wzb.z, hbb.z)), 0.f);
            h1v[7] = fmaxf(fmaf(xv1, wxb.w, fmaf(zv1, wzb.w, hbb.w)), 0.f);

            FragU a0, a1, bf;
            a0.u[0] = pack_bf16(h0[0], h0[1]);
            a0.u[1] = pack_bf16(h0[2], h0[3]);
            a0.u[2] = pack_bf16(h0[4], h0[5]);
            a0.u[3] = pack_bf16(h0[6], h0[7]);
            a1.u[0] = pack_bf16(h1v[0], h1v[1]);
            a1.u[1] = pack_bf16(h1v[2], h1v[3]);
            a1.u[2] = pack_bf16(h1v[4], h1v[5]);
            a1.u[3] = pack_bf16(h1v[6], h1v[7]);
            bf.u[0] = realB ? sh.ia.lpw1[pBl][0][jj] : 0u;
            bf.u[1] = realB ? sh.ia.lpw1[pBl][1][jj] : 0u;
            bf.u[2] = realB ? sh.ia.lpw1[pBl][2][jj] : 0u;
            bf.u[3] = realB ? sh.ia.lpw1[pBl][3][jj] : 0u;

            const float pbv = sh.ia.lpb[pBl][jj];
            const float w2v = sh.ia.lpw2[pBl][jj];

            // pb1 folded into MFMA C operand (one cpb serves both tiles)
            f32x16 cpb;
            #pragma unroll
            for (int r = 0; r < 16; ++r) cpb[r] = pbv;

            f32x16 d0 = __builtin_amdgcn_mfma_f32_32x32x16_bf16(a0.v, bf.v, cpb, 0, 0, 0);
            f32x16 d1 = __builtin_amdgcn_mfma_f32_32x32x16_bf16(a1.v, bf.v, cpb, 0, 0, 0);

            #pragma unroll
            for (int r = 0; r < 16; ++r)
                acc0[r] = fmaf(fmaxf(d0[r], 0.f), w2v, acc0[r]);
            #pragma unroll
            for (int r = 0; r < 16; ++r)
                acc1[r] = fmaf(fmaxf(d1[r], 0.f), w2v, acc1[r]);
        }

        // phased reduction: waves 0,1 write; waves 2,3 accumulate
        const int rb0 = (w & 1) * 64;
        if (w < 2) {
            #pragma unroll
            for (int r = 0; r < 16; ++r) {
                int rowf = (r & 3) + 8 * (r >> 2) + 4 * kh;
                sh.ia.red[rb0 + rowf][m]      = acc0[r];
                sh.ia.red[rb0 + 32 + rowf][m] = acc1[r];
            }
        }
        __syncthreads();
        if (w >= 2) {
            #pragma unroll
            for (int r = 0; r < 16; ++r) {
                int rowf = (r & 3) + 8 * (r >> 2) + 4 * kh;
                sh.ia.red[rb0 + rowf][m]      += acc0[r];
                sh.ia.red[rb0 + 32 + rowf][m] += acc1[r];
            }
        }
        __syncthreads();
        if (t < 128) {
            float s = 0.f;
            #pragma unroll
            for (int c = 0; c < 32; ++c) s += sh.ia.red[t][c];
            atomicAdd(out + b0 + t, s);
        }
    } else {
        // --------------------------- main-MLP role ---------------------------
        const int r2    = bid - NBLK_IA;
        const int btile = r2 & 127;
        const int hf    = (r2 >> 7) & 1;
        const int which = (r2 >> 8) & 1;
        const float* in = which ? z   : x;
        const float* w1 = which ? zw1 : xw1;
        const float* b1 = which ? zb1 : xb1;
        const float* w2 = which ? zw2 : xw2;
        const float* b2 = which ? zb2 : xb2;
        const float* w3 = which ? zw3 : xw3;
        const float* b3 = which ? zb3 : xb3;

        const int wu = __builtin_amdgcn_readfirstlane(w);
        const int b0 = btile * 64;

        // input row in registers (no LDS stage, no barrier)
        float xr[32];
        const float4* xrp = reinterpret_cast<const float4*>(in + (size_t)(b0 + lane) * 32);
        #pragma unroll
        for (int q = 0; q < 8; ++q) {
            float4 v = xrp[q];
            xr[4*q] = v.x; xr[4*q+1] = v.y; xr[4*q+2] = v.z; xr[4*q+3] = v.w;
        }

        // phase A: h1[j], j in [32wu, 32wu+32), lane = batch
        float h1[32];
        #pragma unroll
        for (int j = 0; j < 32; ++j) h1[j] = b1[wu*32 + j];
        #pragma unroll
        for (int mm = 0; mm < 32; ++mm) {
            float xv = xr[mm];
            #pragma unroll
            for (int j = 0; j < 32; ++j)
                h1[j] = fmaf(xv, w1[mm*H1 + wu*32 + j], h1[j]);
        }
        #pragma unroll
        for (int j = 0; j < 32; ++j)
            sh.mm.h1T[wu*32 + j][lane] = fmaxf(h1[j], 0.f);
        __syncthreads();

        // phase B: h2[n], n in [hf*32 + 8wu, +8)
        const int n0 = __builtin_amdgcn_readfirstlane(hf*32 + wu*8);
        float h2[8];
        #pragma unroll
        for (int n = 0; n < 8; ++n) h2[n] = b2[n0 + n];
        #pragma unroll 4
        for (int mm = 0; mm < 128; ++mm) {
            float hv = sh.mm.h1T[mm][lane];
            #pragma unroll
            for (int n = 0; n < 8; ++n)
                h2[n] = fmaf(hv, w2[mm*H2 + n0 + n], h2[n]);
        }
        float p = 0.f;
        #pragma unroll
        for (int n = 0; n < 8; ++n)
            p = fmaf(fmaxf(h2[n], 0.f), w3[n0 + n], p);

        sh.mm.red2[wu][lane] = p;
        __syncthreads();
        if (wu == 0) {
            float s = sh.mm.red2[0][lane] + sh.mm.red2[1][lane]
                    + sh.mm.red2[2][lane] + sh.mm.red2[3][lane];
            if (hf == 0) s += b3[0];
            atomicAdd(out + b0 + lane, s);
        }
    }
}

extern "C" void kernel_launch(void* const* d_in, const int* in_sizes, int n_in,
                              void* d_out, int out_size, void* d_ws, size_t ws_size,
                              hipStream_t stream) {
    const float* x   = (const float*)d_in[0];
    const float* z   = (const float*)d_in[1];
    const float* xw1 = (const float*)d_in[2];
    const float* xb1 = (const float*)d_in[3];
    const float* xw2 = (const float*)d_in[4];
    const float* xb2 = (const float*)d_in[5];
    const float* xw3 = (const float*)d_in[6];
    const float* xb3 = (const float*)d_in[7];
    const float* zw1 = (const float*)d_in[8];
    const float* zb1 = (const float*)d_in[9];
    const float* zw2 = (const float*)d_in[10];
    const float* zb2 = (const float*)d_in[11];
    const float* zw3 = (const float*)d_in[12];
    const float* zb3 = (const float*)d_in[13];
    const float* xzw = (const float*)d_in[14];
    const float* xzb = (const float*)d_in[15];
    const float* pw1 = (const float*)d_in[16];
    const float* pb1 = (const float*)d_in[17];
    const float* pw2 = (const float*)d_in[18];
    float* out = (float*)d_out;

    hipMemsetAsync(out, 0, (size_t)out_size * sizeof(float), stream);

    fused_k<<<dim3(NBLK_IA + NBLK_MM), 256, 0, stream>>>(
        x, z, xw1, xb1, xw2, xb2, xw3, xb3,
        zw1, zb1, zw2, zb2, zw3, zb3,
        xzw, xzb, pw1, pb1, pw2, out);
}